// Round 1
// baseline (256.703 us; speedup 1.0000x reference)
//
#include <hip/hip_runtime.h>

// PyramidROIAlign: B=2, N=1000, C=256, pool 7x7, levels p2..p5 (256,128,64,32), NHWC fp32.
// 256-thread blocks, 4 waves; each wave processes 4 consecutive cells interleaved
// (16 corner loads in flight per wave -> 16 KB outstanding, targets scatter-read latency).
// lane = float4 channel group. Non-temporal output stores keep the 100 MB output
// stream out of L2 so p2 feature lines stay resident.

#define NB 2
#define NN 1000
#define NC 256
#define NCELLS (NB * NN * 49)        // 98000
#define CELLS_PER_WAVE 4
#define WAVES_PER_BLOCK 4
#define CELLS_PER_BLOCK (CELLS_PER_WAVE * WAVES_PER_BLOCK)   // 16; 98000/16 = 6125 exact

typedef float vfloat4 __attribute__((ext_vector_type(4)));   // clang-native, ok for nontemporal builtins

__device__ __forceinline__ void cell_setup(
    int cell,
    const float* __restrict__ boxes,
    const float* __restrict__ p2, const float* __restrict__ p3,
    const float* __restrict__ p4, const float* __restrict__ p5,
    const vfloat4*& a00, const vfloat4*& a01, const vfloat4*& a10, const vfloat4*& a11,
    float& wx, float& wy)
{
    const int pxy = cell % 49;
    const int bn  = cell / 49;
    const int py  = pxy / 7;
    const int px  = pxy % 7;
    const int b   = bn / NN;

    const vfloat4 bx = *(const vfloat4*)(boxes + (size_t)bn * 4);
    const float y1 = bx.x, x1 = bx.y, y2 = bx.z, x2 = bx.w;
    const float h = y2 - y1, w = x2 - x1;

    // roi_level = clip(round(log2(sqrt(max(h*w,1e-12)) / (224/1024))), 2, 5); rintf = half-to-even.
    const float roi = log2f(sqrtf(fmaxf(h * w, 1e-12f)) * (1024.0f / 224.0f));
    int lvl = (int)rintf(roi);
    lvl = min(5, max(2, lvl));

    const float* feat;
    int H;
    switch (lvl) {
        case 2:  feat = p2; H = 256; break;
        case 3:  feat = p3; H = 128; break;
        case 4:  feat = p4; H = 64;  break;
        default: feat = p5; H = 32;  break;
    }
    const int W = H;

    const float ys = (y1 + h * ((float)py * (1.0f / 6.0f))) * (float)(H - 1);
    const float xs = (x1 + w * ((float)px * (1.0f / 6.0f))) * (float)(W - 1);
    const float y0f = floorf(ys), x0f = floorf(xs);
    wy = ys - y0f;
    wx = xs - x0f;
    const int y0 = min(H - 1, max(0, (int)y0f));
    const int yb = min(H - 1, max(0, (int)y0f + 1));
    const int x0 = min(W - 1, max(0, (int)x0f));
    const int xb = min(W - 1, max(0, (int)x0f + 1));

    const size_t base = (size_t)b * H * W * NC;
    a00 = (const vfloat4*)(feat + base + ((size_t)y0 * W + x0) * NC);
    a01 = (const vfloat4*)(feat + base + ((size_t)y0 * W + xb) * NC);
    a10 = (const vfloat4*)(feat + base + ((size_t)yb * W + x0) * NC);
    a11 = (const vfloat4*)(feat + base + ((size_t)yb * W + xb) * NC);
}

__device__ __forceinline__ vfloat4 bilerp4(vfloat4 v00, vfloat4 v01, vfloat4 v10, vfloat4 v11,
                                           float wx, float wy)
{
    vfloat4 top = v00 + wx * (v01 - v00);
    vfloat4 bot = v10 + wx * (v11 - v10);
    return top + wy * (bot - top);
}

__global__ __launch_bounds__(256) void roi_align_kernel(
    const float* __restrict__ boxes,
    const float* __restrict__ p2,
    const float* __restrict__ p3,
    const float* __restrict__ p4,
    const float* __restrict__ p5,
    float* __restrict__ out)
{
    const int lane = threadIdx.x & 63;
    const int wave = threadIdx.x >> 6;

    const int cbase = (blockIdx.x * WAVES_PER_BLOCK + wave) * CELLS_PER_WAVE;

    const vfloat4* a00[CELLS_PER_WAVE];
    const vfloat4* a01[CELLS_PER_WAVE];
    const vfloat4* a10[CELLS_PER_WAVE];
    const vfloat4* a11[CELLS_PER_WAVE];
    float wx[CELLS_PER_WAVE], wy[CELLS_PER_WAVE];

#pragma unroll
    for (int i = 0; i < CELLS_PER_WAVE; ++i) {
        cell_setup(cbase + i, boxes, p2, p3, p4, p5,
                   a00[i], a01[i], a10[i], a11[i], wx[i], wy[i]);
    }

    // Issue all 16 corner loads before any use -> 16 outstanding vmem per wave.
    vfloat4 v00[CELLS_PER_WAVE], v01[CELLS_PER_WAVE], v10[CELLS_PER_WAVE], v11[CELLS_PER_WAVE];
#pragma unroll
    for (int i = 0; i < CELLS_PER_WAVE; ++i) {
        v00[i] = a00[i][lane];
        v01[i] = a01[i][lane];
        v10[i] = a10[i][lane];
        v11[i] = a11[i][lane];
    }

#pragma unroll
    for (int i = 0; i < CELLS_PER_WAVE; ++i) {
        const vfloat4 r = bilerp4(v00[i], v01[i], v10[i], v11[i], wx[i], wy[i]);
        vfloat4* o = (vfloat4*)(out + (size_t)(cbase + i) * NC) + lane;
        __builtin_nontemporal_store(r, o);
    }
}

extern "C" void kernel_launch(void* const* d_in, const int* in_sizes, int n_in,
                              void* d_out, int out_size, void* d_ws, size_t ws_size,
                              hipStream_t stream) {
    const float* boxes = (const float*)d_in[0];
    const float* p2    = (const float*)d_in[1];
    const float* p3    = (const float*)d_in[2];
    const float* p4    = (const float*)d_in[3];
    const float* p5    = (const float*)d_in[4];
    float* out = (float*)d_out;

    const int n_blocks = NCELLS / CELLS_PER_BLOCK;  // 6125
    roi_align_kernel<<<n_blocks, 256, 0, stream>>>(boxes, p2, p3, p4, p5, out);
}